// Round 6
// baseline (174.398 us; speedup 1.0000x reference)
//
#include <hip/hip_runtime.h>

// ---------------- problem constants ----------------
#define B_SAMPLES 8192
#define HID       512
#define NCLS      10
#define STYLE_D   64
#define LATENT_D  16

#define RPB 32                             // rows per block (sorted domain)
#define MAXT    (B_SAMPLES/RPB + NCLS)     // 266 worst-case row tiles
#define MAXROWS (B_SAMPLES + NCLS*RPB)     // 8512 padded sorted rows

typedef short v8s __attribute__((ext_vector_type(8)));
typedef float v4f __attribute__((ext_vector_type(4)));

__device__ __forceinline__ short f2bf(float f) {
    union { float f; unsigned u; } x; x.f = f;
    unsigned r = x.u + 0x7fffu + ((x.u >> 16) & 1u);   // RNE; inputs finite
    return (short)(r >> 16);
}

__device__ __forceinline__ void gload16(const short* g, short* l) {
    __builtin_amdgcn_global_load_lds(
        (const __attribute__((address_space(1))) void*)g,
        (__attribute__((address_space(3))) void*)l, 16, 0, 0);
}

// swizzled half-index into act[32][512]: XOR 16B-chunk within each 64-elem slice
__device__ __forceinline__ int aoff(int m, int k) {
    return m * 512 + (k & ~63) + (((((k >> 3) & 7) ^ (m & 7))) << 3) + (k & 7);
}
// same swizzle for global weight rows (row n, row length = KSRC)
__device__ __forceinline__ int kswz(int n, int k) {
    return (k & ~63) + (((((k >> 3) & 7) ^ (n & 7))) << 3) + (k & 7);
}

// ---------------- grouping (one block) ----------------
// order (pos->sample, -1 in padding), tclass per 32-row tile (-1 = unused).
__global__ void build_groups(const int* __restrict__ y, int* __restrict__ tclass,
                             int* __restrict__ order) {
    __shared__ int cnt[NCLS], cur[NCLS];
    int t = threadIdx.x;                       // 1024 threads
    if (t < NCLS) cnt[t] = 0;
    __syncthreads();
    for (int b = t; b < B_SAMPLES; b += 1024) atomicAdd(&cnt[y[b]], 1);
    __syncthreads();
    if (t == 0) {
        int off = 0, tt = 0;
        for (int c = 0; c < NCLS; ++c) {
            cur[c] = off;
            int nt = (cnt[c] + RPB - 1) / RPB;
            for (int j = 0; j < nt; ++j) tclass[tt++] = c;
            off += nt * RPB;
        }
        for (int u = tt; u < MAXT; ++u) tclass[u] = -1;
    }
    __syncthreads();
    for (int i = t; i < MAXROWS; i += 1024) order[i] = -1;
    __syncthreads();
    for (int b = t; b < B_SAMPLES; b += 1024) {
        int c = y[b];
        int p = atomicAdd(&cur[c], 1);
        order[p] = b;
    }
}

// wt0 [512][64] bf16: transposed sw0, K-padded, pre-swizzled rows
__global__ void prep_wt0(const float* __restrict__ sw0, short* __restrict__ wt0) {
    int idx = blockIdx.x * 256 + threadIdx.x;  // 512*64
    int n = idx >> 6, k = idx & 63;
    wt0[n * 64 + kswz(n, k)] = f2bf(k < LATENT_D ? sw0[(size_t)k * HID + n] : 0.f);
}

// mega transpose (pre-swizzled writes). grid (20,16,34).
// z<33 (bx<16): 512x512 slices (sw1,sw2,sw3,uw0[10],uw1[10],uw2[10])
// z==33 (bx<20): uw3, cls = bx>>1, n0 = (bx&1)*32 -> [64][512] rows
__global__ void transpose_mega(const float* __restrict__ sw1, const float* __restrict__ sw2,
                               const float* __restrict__ sw3, const float* __restrict__ uw0,
                               const float* __restrict__ uw1, const float* __restrict__ uw2,
                               const float* __restrict__ uw3,
                               short* __restrict__ wt1, short* __restrict__ wt2,
                               short* __restrict__ wt3, short* __restrict__ wtu0,
                               short* __restrict__ wtu1, short* __restrict__ wtu2,
                               short* __restrict__ wtu3) {
    __shared__ float tile[32][33];
    int zz = blockIdx.z;
    int tx = threadIdx.x, ty = threadIdx.y;    // 32 x 8
    if (zz == 33) {
        int cls = blockIdx.x >> 1;             // 0..9
        int n0 = (blockIdx.x & 1) * 32, k0 = blockIdx.y * 32;
        const float* s = uw3  + (size_t)cls * HID * STYLE_D;
        short*       d = wtu3 + (size_t)cls * STYLE_D * HID;
        #pragma unroll
        for (int j = 0; j < 32; j += 8)
            tile[ty + j][tx] = s[(size_t)(k0 + ty + j) * STYLE_D + n0 + tx];
        __syncthreads();
        #pragma unroll
        for (int j = 0; j < 32; j += 8) {
            int n = n0 + ty + j, k = k0 + tx;
            d[(size_t)n * HID + kswz(n, k)] = f2bf(tile[tx][ty + j]);
        }
        return;
    }
    if (blockIdx.x >= 16) return;
    const float* s; short* d;
    if      (zz == 0) { s = sw1; d = wt1; }
    else if (zz == 1) { s = sw2; d = wt2; }
    else if (zz == 2) { s = sw3; d = wt3; }
    else if (zz < 13) { size_t o = (size_t)(zz - 3)  * HID * HID; s = uw0 + o; d = wtu0 + o; }
    else if (zz < 23) { size_t o = (size_t)(zz - 13) * HID * HID; s = uw1 + o; d = wtu1 + o; }
    else              { size_t o = (size_t)(zz - 23) * HID * HID; s = uw2 + o; d = wtu2 + o; }
    int n0 = blockIdx.x * 32, k0 = blockIdx.y * 32;
    #pragma unroll
    for (int j = 0; j < 32; j += 8)
        tile[ty + j][tx] = s[(size_t)(k0 + ty + j) * HID + n0 + tx];
    __syncthreads();
    #pragma unroll
    for (int j = 0; j < 32; j += 8) {
        int n = n0 + ty + j, k = k0 + tx;
        d[(size_t)n * HID + kswz(n, k)] = f2bf(tile[tx][ty + j]);
    }
}

// ---------------- fused 8-layer MLP megakernel ----------------
// One block owns 32 sorted rows through all layers. act: LDS bf16 swizzled.
// Weights stream per K-step into ws (pre-swizzled rows -> conflict-free reads).
template <int KSRC, int NSTEPS>
__device__ __forceinline__ void full_layer(
    const short* __restrict__ W, const float* __restrict__ bs,
    short* act, short* ws, int t, int wv, int lrow, int lko) {
    v4f acc[2][4] = {};
    #pragma unroll 1
    for (int ks = 0; ks < NSTEPS; ++ks) {
        #pragma unroll
        for (int r = 0; r < 8; ++r) {
            int n = r * 64 + (t >> 3);
            gload16(W + (size_t)n * KSRC + ks * 64 + (t & 7) * 8,
                    &ws[n * 64 + (t & 7) * 8]);
        }
        __syncthreads();
        #pragma unroll
        for (int kk = 0; kk < 2; ++kk) {
            v8s af[2], bq[4];
            #pragma unroll
            for (int i = 0; i < 2; ++i)
                af[i] = *(const v8s*)&act[aoff(i * 16 + lrow, ks * 64 + kk * 32 + lko * 8)];
            #pragma unroll
            for (int j = 0; j < 4; ++j) {
                int n = wv * 64 + j * 16 + lrow;
                bq[j] = *(const v8s*)&ws[n * 64 + (((kk * 4 + lko) ^ (n & 7)) << 3)];
            }
            #pragma unroll
            for (int i = 0; i < 2; ++i)
                #pragma unroll
                for (int j = 0; j < 4; ++j)
                    acc[i][j] = __builtin_amdgcn_mfma_f32_16x16x32_bf16(
                        af[i], bq[j], acc[i][j], 0, 0, 0);
        }
        __syncthreads();        // ws reads done before next stage / epilogue act-write
    }
    #pragma unroll
    for (int i = 0; i < 2; ++i)
        #pragma unroll
        for (int j = 0; j < 4; ++j)
            #pragma unroll
            for (int q = 0; q < 4; ++q) {
                int m = i * 16 + lko * 4 + q;             // C/D: row=(l>>4)*4+reg
                int n = wv * 64 + j * 16 + lrow;          //      col=l&15
                float v = fmaxf(acc[i][j][q] + bs[n], 0.f);
                act[aoff(m, n)] = f2bf(v);
            }
}

__global__ __launch_bounds__(512, 1) void fused_mlp(
    const float* __restrict__ z, const int* __restrict__ order,
    const int* __restrict__ tclass,
    const short* __restrict__ wt0, const short* __restrict__ wt1,
    const short* __restrict__ wt2, const short* __restrict__ wt3,
    const short* __restrict__ wtu0, const short* __restrict__ wtu1,
    const short* __restrict__ wtu2, const short* __restrict__ wtu3,
    const float* __restrict__ sb0, const float* __restrict__ sb1,
    const float* __restrict__ sb2, const float* __restrict__ sb3,
    const float* __restrict__ ub0, const float* __restrict__ ub1,
    const float* __restrict__ ub2, const float* __restrict__ ub3,
    float* __restrict__ out) {

    const int tile = blockIdx.x;
    const int cls = tclass[tile];
    if (cls < 0) return;
    const int p0 = tile * RPB;

    __shared__ short act[RPB * HID];           // 32 KB
    __shared__ short ws[HID * 64];             // 64 KB

    const int t = threadIdx.x, lane = t & 63, wv = t >> 6;
    const int lrow = lane & 15, lko = lane >> 4;

    // layer-0 input: gather z rows into act (K-padded to 64, swizzled)
    #pragma unroll
    for (int i = 0; i < 4; ++i) {
        int idx = i * 512 + t;                 // 32 rows x 64 k
        int m = idx >> 6, k = idx & 63;
        int o = order[p0 + m];
        float v = (o >= 0 && k < LATENT_D) ? z[(size_t)o * LATENT_D + k] : 0.f;
        act[aoff(m, k)] = f2bf(v);
    }
    // NOTE: no barrier needed here; full_layer's stage->barrier covers it.

    full_layer<64, 1> (wt0, sb0, act, ws, t, wv, lrow, lko);
    full_layer<512, 8>(wt1, sb1, act, ws, t, wv, lrow, lko);
    full_layer<512, 8>(wt2, sb2, act, ws, t, wv, lrow, lko);
    full_layer<512, 8>(wt3, sb3, act, ws, t, wv, lrow, lko);
    full_layer<512, 8>(wtu0 + (size_t)cls * HID * HID, ub0 + cls * HID,
                       act, ws, t, wv, lrow, lko);
    full_layer<512, 8>(wtu1 + (size_t)cls * HID * HID, ub1 + cls * HID,
                       act, ws, t, wv, lrow, lko);
    full_layer<512, 8>(wtu2 + (size_t)cls * HID * HID, ub2 + cls * HID,
                       act, ws, t, wv, lrow, lko);

    // layer 7: N=64, no relu, fp32 scatter to out
    {
        const short* W = wtu3 + (size_t)cls * STYLE_D * HID;
        v4f acc[2] = {};
        #pragma unroll 1
        for (int ks = 0; ks < 8; ++ks) {
            int n = t >> 3;                    // 64 rows x 8 chunks = 512 threads
            gload16(W + (size_t)n * HID + ks * 64 + (t & 7) * 8,
                    &ws[n * 64 + (t & 7) * 8]);
            __syncthreads();
            if (wv < 4) {
                #pragma unroll
                for (int kk = 0; kk < 2; ++kk) {
                    v8s af[2], b;
                    #pragma unroll
                    for (int i = 0; i < 2; ++i)
                        af[i] = *(const v8s*)&act[aoff(i * 16 + lrow,
                                                       ks * 64 + kk * 32 + lko * 8)];
                    int n2 = wv * 16 + lrow;
                    b = *(const v8s*)&ws[n2 * 64 + (((kk * 4 + lko) ^ (n2 & 7)) << 3)];
                    #pragma unroll
                    for (int i = 0; i < 2; ++i)
                        acc[i] = __builtin_amdgcn_mfma_f32_16x16x32_bf16(
                            af[i], b, acc[i], 0, 0, 0);
                }
            }
            __syncthreads();
        }
        if (wv < 4) {
            #pragma unroll
            for (int i = 0; i < 2; ++i)
                #pragma unroll
                for (int q = 0; q < 4; ++q) {
                    int m = i * 16 + lko * 4 + q;
                    int c = wv * 16 + lrow;
                    int o = order[p0 + m];
                    if (o >= 0)
                        out[(size_t)o * STYLE_D + c] = acc[i][q] + ub3[cls * STYLE_D + c];
                }
        }
    }
}

// ---------------- launcher ----------------
extern "C" void kernel_launch(void* const* d_in, const int* in_sizes, int n_in,
                              void* d_out, int out_size, void* d_ws, size_t ws_size,
                              hipStream_t stream) {
    const float* z   = (const float*)d_in[0];
    const int*   y   = (const int*)d_in[1];
    const float* sw0 = (const float*)d_in[2];
    const float* sb0 = (const float*)d_in[3];
    const float* sw1 = (const float*)d_in[4];
    const float* sb1 = (const float*)d_in[5];
    const float* sw2 = (const float*)d_in[6];
    const float* sb2 = (const float*)d_in[7];
    const float* sw3 = (const float*)d_in[8];
    const float* sb3 = (const float*)d_in[9];
    const float* uw0 = (const float*)d_in[10];
    const float* ub0 = (const float*)d_in[11];
    const float* uw1 = (const float*)d_in[12];
    const float* ub1 = (const float*)d_in[13];
    const float* uw2 = (const float*)d_in[14];
    const float* ub2 = (const float*)d_in[15];
    const float* uw3 = (const float*)d_in[16];
    const float* ub3 = (const float*)d_in[17];

    char* p = (char*)d_ws;
    auto alloc = [&](size_t bytes) -> char* {
        char* r = p; p += (bytes + 255) & ~(size_t)255; return r;
    };
    int*   tclass = (int*)alloc(MAXT * 4);
    int*   order  = (int*)alloc(MAXROWS * 4);
    short* wt0    = (short*)alloc((size_t)HID * 64 * 2);
    short* wt1    = (short*)alloc((size_t)HID * HID * 2);
    short* wt2    = (short*)alloc((size_t)HID * HID * 2);
    short* wt3    = (short*)alloc((size_t)HID * HID * 2);
    short* wtu0   = (short*)alloc((size_t)NCLS * HID * HID * 2);
    short* wtu1   = (short*)alloc((size_t)NCLS * HID * HID * 2);
    short* wtu2   = (short*)alloc((size_t)NCLS * HID * HID * 2);
    short* wtu3   = (short*)alloc((size_t)NCLS * STYLE_D * HID * 2);

    build_groups<<<1, 1024, 0, stream>>>(y, tclass, order);
    prep_wt0<<<(HID * 64) / 256, 256, 0, stream>>>(sw0, wt0);
    dim3 tb(32, 8);
    transpose_mega<<<dim3(20, 16, 34), tb, 0, stream>>>(sw1, sw2, sw3, uw0, uw1, uw2, uw3,
                                                        wt1, wt2, wt3, wtu0, wtu1, wtu2, wtu3);

    fused_mlp<<<MAXT, 512, 0, stream>>>(
        z, order, tclass,
        wt0, wt1, wt2, wt3, wtu0, wtu1, wtu2, wtu3,
        sb0, sb1, sb2, sb3, ub0, ub1, ub2, ub3,
        (float*)d_out);
}